// Round 24
// baseline (123.326 us; speedup 1.0000x reference)
//
#include <hip/hip_runtime.h>
#include <hip/hip_bf16.h>

#define NROWS 16384
#define DIM   256
#define DB    (DIM / 2)               // 128 bytes per fp4 row
#define SEGS  8
#define BN    128                     // staged tile: 128 cols x 256 k (fp4) = 16 KB
#define TB    (BN * DB)               // 16384 bytes per staged tile
#define NT    ((NROWS / SEGS) / BN)   // 16 tiles per segment
#define INVT  14.285714285714286f
#define C1f   20.60992915555662f      // log2(e)/0.07 ; A is pre-scaled by this
#define LN2f  0.6931471805599453f

typedef __attribute__((ext_vector_type(8)))  int   int8v;    // MFMA operand (fp4 uses low 4 regs)
typedef __attribute__((ext_vector_type(16))) float f32x16;   // 32x32 MFMA accumulator

#define SCA 0x7F7F7F7Fu   // E8M0 = 2^0   (A scale; A pre-scaled by C1, sigma~1.29)
#define SCB 0x7B7B7B7Bu   // E8M0 = 2^-4  (B scale; B pre-multiplied by 16, sigma~1.0)

// fp4 e2m1 RNE quantize: codes 0..7 = {0, .5, 1, 1.5, 2, 3, 4, 6} (monotonic), bit3 = sign
__device__ __forceinline__ unsigned fp4q(float v) {
    float a = fabsf(v);
    unsigned s = (__float_as_uint(v) >> 28) & 0x8u;
    unsigned idx = (unsigned)(a >= 0.25f) + (a >= 0.75f) + (a >= 1.25f) + (a >= 1.75f)
                 + (a >= 2.5f) + (a >= 3.5f) + (a >= 5.0f);
    return s | idx;
}

// Kernel 1: L2-normalize (fp32); emit fp4 A (row-major, xC1) and fp4 B (x16) in the
// DMA staging layout, plus exact fp32 diagonal. One wave per row.
// B layout (16B chunks of the 128B fp4 row): chunk(col,kcb4) = (col>>7)*1024
//     + ((col>>6)&1)*512 + kcb4*64 + (col&63),   kcb4 = 16B chunk along K (0..7)
__global__ __launch_bounds__(256) void norm_diag_kernel(
    const float* __restrict__ fl, const float* __restrict__ fg,
    unsigned char* __restrict__ A, unsigned char* __restrict__ B,
    float* __restrict__ diag, float* __restrict__ out)
{
    int tid  = threadIdx.x;
    int wave = tid >> 6, lane = tid & 63;
    int row  = blockIdx.x * 4 + wave;
    if (blockIdx.x == 0 && tid == 0) out[0] = 0.0f;   // zero accumulator for final atomicAdd

    float4 xl = ((const float4*)(fl + (size_t)row * DIM))[lane];
    float4 xg = ((const float4*)(fg + (size_t)row * DIM))[lane];
    float ssl = xl.x*xl.x + xl.y*xl.y + xl.z*xl.z + xl.w*xl.w;
    float ssg = xg.x*xg.x + xg.y*xg.y + xg.z*xg.z + xg.w*xg.w;
    for (int m = 1; m < 64; m <<= 1) {
        ssl += __shfl_xor(ssl, m, 64);
        ssg += __shfl_xor(ssg, m, 64);
    }
    float il = 1.0f / fmaxf(sqrtf(ssl), 1e-12f);
    float ig = 1.0f / fmaxf(sqrtf(ssg), 1e-12f);
    float nl0 = xl.x*il, nl1 = xl.y*il, nl2 = xl.z*il, nl3 = xl.w*il;
    float ng0 = xg.x*ig, ng1 = xg.y*ig, ng2 = xg.z*ig, ng3 = xg.w*ig;

    // A: quantize C1*nl to fp4 (scale 2^0 at MFMA); lane holds k = 4*lane..4*lane+3
    unsigned pa4 = fp4q(nl0 * C1f) | (fp4q(nl1 * C1f) << 4)
                 | (fp4q(nl2 * C1f) << 8) | (fp4q(nl3 * C1f) << 12);
    ((unsigned short*)(A + (size_t)row * DB))[lane] = (unsigned short)pa4;

    // B: quantize 16*ng to fp4 (scale 2^-4 at MFMA), store into staging layout
    unsigned pb4 = fp4q(ng0 * 16.0f) | (fp4q(ng1 * 16.0f) << 4)
                 | (fp4q(ng2 * 16.0f) << 8) | (fp4q(ng3 * 16.0f) << 12);
    {
        int kcb4 = lane >> 3;         // 16B chunk along K (0..7)
        unsigned chunk = (unsigned)((row >> 7) * 1024 + ((row >> 6) & 1) * 512
                                    + kcb4 * 64 + (row & 63));
        ((unsigned short*)B)[chunk * 8 + (lane & 7)] = (unsigned short)pb4;
    }

    float d = nl0*ng0 + nl1*ng1 + nl2*ng2 + nl3*ng3;   // exact fp32 diagonal
    for (int m = 1; m < 64; m <<= 1) d += __shfl_xor(d, m, 64);
    if (lane == 0) diag[row] = d;
}

// Kernel 2: fused sim-GEMM + fixed-max sumexp, MX-fp4 32x32x64 (fmt=4).
// R23 frame (48.4 us) with the previous unit's 32-exp2 epilogue interleaved
// 4-per-MFMA inside the chain. Liveness is IDENTICAL to R23 (both acc sets,
// af, lv, bf already co-live there) -- source order is the only change, so the
// fp4 register slack (VGPR 84) should hold. VALU fills the MFMA occupancy.
__global__ __launch_bounds__(256, 2) void sim_lse_kernel(
    const unsigned char* __restrict__ A, const unsigned char* __restrict__ B,
    float* __restrict__ lpart)
{
    __shared__ __align__(16) unsigned char bt[2 * TB];   // 2 x 16 KB double buffer

    int tid  = threadIdx.x;
    int lane = tid & 63;
    int l31  = lane & 31, half = lane >> 5;
    int wave = tid >> 6;
    int seg  = blockIdx.x;
    int rowBase = blockIdx.y * 256 + wave * 64;

    unsigned vb = (unsigned)(l31 * 16 + half * 1024);   // LDS read base

    const int4 zero4 = make_int4(0, 0, 0, 0);

    // Preload A fragments (fp4: 16B per fragment, high half zeroed)
    int8v af[2][4];
#pragma unroll
    for (int s = 0; s < 2; ++s) {
        const unsigned char* ap = A + (size_t)(rowBase + s*32 + l31) * DB + half * 16;
#pragma unroll
        for (int kk = 0; kk < 4; ++kk) {
            ((int4*)&af[s][kk])[0] = *(const int4*)(ap + kk * 32);
            ((int4*)&af[s][kk])[1] = zero4;
        }
    }

    f32x16 lv[2];
    f32x16 Z;
    f32x16 accA[2], accB[2];
#pragma unroll
    for (int r = 0; r < 16; ++r) {
        lv[0][r] = -1.0f; lv[1][r] = -1.0f;   // compensate the one dummy epilogue
        Z[r] = 0.0f;
        accB[0][r] = 0.0f; accB[1][r] = 0.0f; // dummy-epilogue source
    }

    int T0 = seg * NT;

    auto stage = [&](int T, unsigned bufo) {
        const unsigned char* g = B + (size_t)T * TB + (unsigned)tid * 16;
        unsigned lo = bufo + (unsigned)tid * 16;
#pragma unroll
        for (int j = 0; j < 4; ++j) {
            __builtin_amdgcn_global_load_lds(
                (const __attribute__((address_space(1))) unsigned int*)(g + j * 4096),
                (__attribute__((address_space(3))) unsigned int*)&bt[lo + j * 4096],
                16, 0, 0);
        }
    };

#define MFMA4(dst, a, b, cin) \
    dst = __builtin_amdgcn_mfma_scale_f32_32x32x64_f8f6f4(a, b, cin, 4, 4, 0, SCA, 0, SCB)
#define EP4(S, R) \
    lv[S][R+0] += __builtin_amdgcn_exp2f(pv[S][R+0]); \
    lv[S][R+1] += __builtin_amdgcn_exp2f(pv[S][R+1]); \
    lv[S][R+2] += __builtin_amdgcn_exp2f(pv[S][R+2]); \
    lv[S][R+3] += __builtin_amdgcn_exp2f(pv[S][R+3]);

    // One 64x32 unit (8 MFMAs) with the PREVIOUS unit's epilogue interleaved
    // 4 exp2 per MFMA. pv is fully consumed by the end; ac fully produced.
    auto chain_epi = [&](f32x16 (&ac)[2], f32x16 (&pv)[2], unsigned ab, unsigned offc) {
        int8v b0, b1;
        ((int4*)&b0)[1] = zero4; ((int4*)&b1)[1] = zero4;
        ((int4*)&b0)[0] = *(const int4*)&bt[ab + offc];           // kk=0
        ((int4*)&b1)[0] = *(const int4*)&bt[ab + offc + 2048u];   // kk=1
        MFMA4(ac[0], af[0][0], b0, Z);   EP4(0, 0)
        MFMA4(ac[1], af[1][0], b0, Z);   EP4(1, 0)
        ((int4*)&b0)[0] = *(const int4*)&bt[ab + offc + 4096u];   // kk=2
        MFMA4(ac[0], af[0][1], b1, ac[0]);   EP4(0, 4)
        MFMA4(ac[1], af[1][1], b1, ac[1]);   EP4(1, 4)
        ((int4*)&b1)[0] = *(const int4*)&bt[ab + offc + 6144u];   // kk=3
        MFMA4(ac[0], af[0][2], b0, ac[0]);   EP4(0, 8)
        MFMA4(ac[1], af[1][2], b0, ac[1]);   EP4(1, 8)
        MFMA4(ac[0], af[0][3], b1, ac[0]);   EP4(0, 12)
        MFMA4(ac[1], af[1][3], b1, ac[1]);   EP4(1, 12)
    };

    stage(T0, 0);

    for (int t = 0; t < NT; ++t) {
        unsigned bufo = (t & 1) ? (unsigned)TB : 0u;
        __syncthreads();   // drains own tile-t DMA (in flight a full tile), syncs waves

        if (t + 1 < NT)
            stage(T0 + t + 1, (t & 1) ? 0u : (unsigned)TB);

        unsigned ab = vb + bufo;
        chain_epi(accA, accB, ab, 0u);      // cols  0-31 (dummy prev at t=0)
        chain_epi(accB, accA, ab, 512u);    // cols 32-63
        chain_epi(accA, accB, ab, 8192u);   // cols 64-95
        chain_epi(accB, accA, ab, 8704u);   // cols 96-127
    }
    // Final unit's epilogue
#pragma unroll
    for (int s = 0; s < 2; ++s)
#pragma unroll
        for (int r = 0; r < 16; ++r)
            lv[s][r] += __builtin_amdgcn_exp2f(accB[s][r]);

    // Sum across the 32 column-lanes
#pragma unroll
    for (int s = 0; s < 2; ++s)
#pragma unroll
        for (int r = 0; r < 16; ++r) {
            float v = lv[s][r];
            v += __shfl_xor(v, 1, 64);
            v += __shfl_xor(v, 2, 64);
            v += __shfl_xor(v, 4, 64);
            v += __shfl_xor(v, 8, 64);
            v += __shfl_xor(v, 16, 64);
            lv[s][r] = v;
        }
    if (l31 == 0) {
#pragma unroll
        for (int s = 0; s < 2; ++s)
#pragma unroll
            for (int r = 0; r < 16; ++r) {
                int row = rowBase + s*32 + (r & 3) + 8*(r >> 2) + 4*half;
                lpart[(size_t)seg * NROWS + row] = lv[s][r];
            }
    }
#undef MFMA4
#undef EP4
}

// Kernel 3: loss_i = -invT*diag_i + ln2*log2(sum_seg l_part), then mean via atomicAdd.
__global__ __launch_bounds__(256) void reduce_kernel(
    const float* __restrict__ lpart, const float* __restrict__ diag,
    float* __restrict__ out)
{
    __shared__ float sm[4];
    int gtid = blockIdx.x * 256 + threadIdx.x;
    float s = 0.0f;
    for (int row = gtid; row < NROWS; row += 32 * 256) {
        float t = 0.0f;
#pragma unroll
        for (int g = 0; g < SEGS; ++g) t += lpart[(size_t)g * NROWS + row];
        s += LN2f * log2f(t) - INVT * diag[row];
    }
    for (int m = 1; m < 64; m <<= 1) s += __shfl_xor(s, m, 64);
    int wave = threadIdx.x >> 6, lane = threadIdx.x & 63;
    if (lane == 0) sm[wave] = s;
    __syncthreads();
    if (threadIdx.x == 0) {
        float tot = sm[0] + sm[1] + sm[2] + sm[3];
        atomicAdd(out, tot * (1.0f / NROWS));
    }
}

extern "C" void kernel_launch(void* const* d_in, const int* in_sizes, int n_in,
                              void* d_out, int out_size, void* d_ws, size_t ws_size,
                              hipStream_t stream) {
    const float* fl = (const float*)d_in[0];
    const float* fg = (const float*)d_in[1];
    float* out = (float*)d_out;

    char* ws = (char*)d_ws;
    unsigned char* A = (unsigned char*)ws;                         // 16384*128 = 2 MB (fp4)
    unsigned char* B = A + (size_t)NROWS * DB;                     // 2 MB (fp4, staging layout)
    float* diag  = (float*)(ws + 2 * (size_t)NROWS * DB);          // 64 KB
    float* lpart = diag + NROWS;                                   // SEGS*N*4 = 512 KB

    norm_diag_kernel<<<NROWS / 4, 256, 0, stream>>>(fl, fg, A, B, diag, out);
    sim_lse_kernel<<<dim3(SEGS, NROWS / 256), 256, 0, stream>>>(A, B, lpart);
    reduce_kernel<<<32, 256, 0, stream>>>(lpart, diag, out);
}